// Round 2
// baseline (2035.277 us; speedup 1.0000x reference)
//
#include <hip/hip_runtime.h>
#include <hip/hip_bf16.h>

typedef unsigned short u16;
typedef unsigned int u32;
typedef float f32x4_t __attribute__((ext_vector_type(4)));
typedef __bf16 bf16x8_t __attribute__((ext_vector_type(8)));

#define NB 16384
#define TT 6
#define CC 1024
#define HH 8
#define HD 128
#define MROWS (NB * TT)          // 98304
#define NCOLS (2 * CC)           // 2048

static __device__ __forceinline__ u16 f2bf(float f) {
    u32 x = __float_as_uint(f);
    u32 r = (x + 0x7fffu + ((x >> 16) & 1u)) >> 16;   // RNE
    return (u16)r;
}
static __device__ __forceinline__ float bf2f(u16 u) {
    return __uint_as_float(((u32)u) << 16);
}

// ---------------------------------------------------------------------------
// K1: pack W = [Wq | Wk] transposed to bf16:  Wt[j][k] = W[k][j], j in [0,2048)
//     bias[j] = [bq | bk]
// ---------------------------------------------------------------------------
__global__ void pack_w_kernel(const float* __restrict__ Wq, const float* __restrict__ Wk,
                              const float* __restrict__ bq, const float* __restrict__ bk,
                              u16* __restrict__ Wt, float* __restrict__ bias) {
    int idx = blockIdx.x * 256 + threadIdx.x;     // 0 .. 2M-1
    int k = idx >> 11;
    int j = idx & 2047;
    float w = (j < 1024) ? Wq[(size_t)k * 1024 + j] : Wk[(size_t)k * 1024 + (j - 1024)];
    Wt[(size_t)j * 1024 + k] = f2bf(w);
    if (idx < 2048) bias[idx] = (idx < 1024) ? bq[idx] : bk[idx - 1024];
}

// ---------------------------------------------------------------------------
// K2: gate[n][j] = ac[n] . Wg[:,j] + bg[j]   (16384 x 6)
// ---------------------------------------------------------------------------
__global__ void gate_kernel(const float* __restrict__ ac, const float* __restrict__ Wg,
                            const float* __restrict__ bg, float* __restrict__ gate) {
    int idx = blockIdx.x * 256 + threadIdx.x;     // n*6+j, 98304 exact
    int n = idx / 6, j = idx - n * 6;
    float s = bg[j];
    const float* a = ac + (size_t)n * 128;
    #pragma unroll 8
    for (int t = 0; t < 128; ++t) s += a[t] * Wg[t * 6 + j];
    gate[idx] = s;
}

// ---------------------------------------------------------------------------
// K3: QK[m][j] = bf16( emb_flat[m] @ W[:,j] + bias[j] )   (98304 x 2048)
//     128x128 tile, BK=64, 4 waves (2x2), double-buffered LDS, reg-staged A
//     (fp32 -> bf16 convert in staging), padded LDS rows (72 bf16 = 144B).
// ---------------------------------------------------------------------------
__launch_bounds__(256, 2)
__global__ void qk_gemm_kernel(const float* __restrict__ A,    // [98304][1024] fp32
                               const u16* __restrict__ Bt,     // [2048][1024] bf16 (W^T)
                               const float* __restrict__ bias, // [2048]
                               u16* __restrict__ Cout) {       // [98304][2048] bf16
    __shared__ alignas(16) u16 As[2][128][72];
    __shared__ alignas(16) u16 Bs[2][128][72];

    const int tid  = threadIdx.x;
    const int lane = tid & 63;
    const int l15  = lane & 15;
    const int lgr  = lane >> 4;
    const int wid  = tid >> 6;
    const int wm = wid >> 1, wn = wid & 1;

    // XCD-aware swizzle: 12288 blocks = 8 XCDs * 1536; group 16 n-tiles per m-tile
    int bid = blockIdx.x;
    int wg  = (bid & 7) * 1536 + (bid >> 3);
    int mt = wg >> 4, nt = wg & 15;
    const int m0 = mt * 128, n0 = nt * 128;

    const float* Aptr = A + (size_t)m0 * 1024;
    const u16*  Bptr  = Bt + (size_t)n0 * 1024;

    float4 areg[8];
    uint4  breg[4];

    auto load_tile = [&](int k0) {
        #pragma unroll
        for (int j = 0; j < 8; ++j) {
            int f = tid + j * 256, r = f >> 4, c = f & 15;
            areg[j] = *reinterpret_cast<const float4*>(Aptr + (size_t)r * 1024 + k0 + c * 4);
        }
        #pragma unroll
        for (int j = 0; j < 4; ++j) {
            int f = tid + j * 256, r = f >> 3, c = f & 7;
            breg[j] = *reinterpret_cast<const uint4*>(Bptr + (size_t)r * 1024 + k0 + c * 8);
        }
    };
    auto store_tile = [&](int buf) {
        #pragma unroll
        for (int j = 0; j < 8; ++j) {
            int f = tid + j * 256, r = f >> 4, c = f & 15;
            uint2 w;
            w.x = ((u32)f2bf(areg[j].y) << 16) | f2bf(areg[j].x);
            w.y = ((u32)f2bf(areg[j].w) << 16) | f2bf(areg[j].z);
            *reinterpret_cast<uint2*>(&As[buf][r][c * 4]) = w;
        }
        #pragma unroll
        for (int j = 0; j < 4; ++j) {
            int f = tid + j * 256, r = f >> 3, c = f & 7;
            *reinterpret_cast<uint4*>(&Bs[buf][r][c * 8]) = breg[j];
        }
    };

    f32x4_t acc[4][4];
    #pragma unroll
    for (int m = 0; m < 4; ++m)
        #pragma unroll
        for (int n = 0; n < 4; ++n) acc[m][n] = f32x4_t{0.f, 0.f, 0.f, 0.f};

    load_tile(0);
    store_tile(0);
    __syncthreads();

    int cur = 0;
    for (int t = 0; t < 16; ++t) {
        if (t < 15) load_tile((t + 1) * 64);
        #pragma unroll
        for (int kk = 0; kk < 2; ++kk) {
            bf16x8_t a[4], b[4];
            #pragma unroll
            for (int m = 0; m < 4; ++m)
                a[m] = *reinterpret_cast<const bf16x8_t*>(&As[cur][wm * 64 + m * 16 + l15][kk * 32 + lgr * 8]);
            #pragma unroll
            for (int n = 0; n < 4; ++n)
                b[n] = *reinterpret_cast<const bf16x8_t*>(&Bs[cur][wn * 64 + n * 16 + l15][kk * 32 + lgr * 8]);
            #pragma unroll
            for (int m = 0; m < 4; ++m)
                #pragma unroll
                for (int n = 0; n < 4; ++n)
                    acc[m][n] = __builtin_amdgcn_mfma_f32_16x16x32_bf16(a[m], b[n], acc[m][n], 0, 0, 0);
        }
        __syncthreads();
        if (t < 15) store_tile(cur ^ 1);
        __syncthreads();
        cur ^= 1;
    }

    // epilogue: C/D layout col = lane&15, row = (lane>>4)*4 + reg  [m89]
    #pragma unroll
    for (int n = 0; n < 4; ++n) {
        int gcol = n0 + wn * 64 + n * 16 + l15;
        float bv = bias[gcol];
        #pragma unroll
        for (int m = 0; m < 4; ++m) {
            int grow = m0 + wm * 64 + m * 16 + lgr * 4;
            #pragma unroll
            for (int r = 0; r < 4; ++r)
                Cout[(size_t)(grow + r) * 2048 + gcol] = f2bf(acc[m][n][r] + bv);
        }
    }
}

// ---------------------------------------------------------------------------
// K4: attention. Block = 4 waves, block <-> n, each wave does heads wid*2, wid*2+1.
//     Per (n,h): stage q,k (6x128 bf16) in wave-private LDS; 4x mfma 16x16x32
//     for scores (rows/cols >=6 are garbage but row/col-contained); masked
//     shfl softmax per 16-lane group; fp32 PV with coalesced ctx stores.
// ---------------------------------------------------------------------------
__launch_bounds__(256)
__global__ void attn_kernel(const u16* __restrict__ QK,     // [98304][2048] bf16
                            const float* __restrict__ emb,  // [16384][6][1024] fp32
                            const float* __restrict__ gate, // [16384][6]
                            float* __restrict__ out) {      // ctx (N*T*C) then attn (N*H*36)
    __shared__ alignas(16) u16 q16[4][16][136];
    __shared__ alignas(16) u16 k16[4][16][136];
    __shared__ alignas(16) float s_lds[4][40];

    const int tid = threadIdx.x, lane = tid & 63, wid = tid >> 6;
    const int n = blockIdx.x;
    const int j = lane & 15;
    const int ghi = lane >> 4;

    for (int it = 0; it < 2; ++it) {
        const int h = wid * 2 + it;
        const size_t rowbase = (size_t)n * 6 * 2048;

        #pragma unroll
        for (int r = 0; r < 6; ++r) {
            u32 qv = *reinterpret_cast<const u32*>(QK + rowbase + (size_t)r * 2048 + h * 128 + lane * 2);
            u32 kv = *reinterpret_cast<const u32*>(QK + rowbase + (size_t)r * 2048 + 1024 + h * 128 + lane * 2);
            *reinterpret_cast<u32*>(&q16[wid][r][lane * 2]) = qv;
            *reinterpret_cast<u32*>(&k16[wid][r][lane * 2]) = kv;
        }
        float v0[6], v1[6];
        #pragma unroll
        for (int r = 0; r < 6; ++r) {
            v0[r] = emb[(size_t)(n * 6 + r) * 1024 + h * 128 + lane];
            v1[r] = emb[(size_t)(n * 6 + r) * 1024 + h * 128 + 64 + lane];
        }
        __syncthreads();

        // scores = q @ k^T : A[i][d] = q16[i][d], B[d][j] = k16[j][d]
        f32x4_t acc = {0.f, 0.f, 0.f, 0.f};
        #pragma unroll
        for (int kk = 0; kk < 4; ++kk) {
            bf16x8_t a = *reinterpret_cast<const bf16x8_t*>(&q16[wid][j][kk * 32 + ghi * 8]);
            bf16x8_t b = *reinterpret_cast<const bf16x8_t*>(&k16[wid][j][kk * 32 + ghi * 8]);
            acc = __builtin_amdgcn_mfma_f32_16x16x32_bf16(a, b, acc, 0, 0, 0);
        }

        float gj = (j < 6) ? gate[n * 6 + j] : 0.f;
        float scale = 0.08838834764831845f * gj;   // 1/sqrt(128) * gate_j

        float sv[4];
        #pragma unroll
        for (int r = 0; r < 4; ++r) {
            float x = (j < 6) ? acc[r] * scale : -1e30f;
            float m = x;
            #pragma unroll
            for (int off = 1; off < 16; off <<= 1) m = fmaxf(m, __shfl_xor(m, off, 16));
            float p = (j < 6) ? __expf(x - m) : 0.f;
            float s = p;
            #pragma unroll
            for (int off = 1; off < 16; off <<= 1) s += __shfl_xor(s, off, 16);
            sv[r] = p / s;
        }

        const size_t attn_base = (size_t)NB * TT * CC + (size_t)(n * 8 + h) * 36;
        #pragma unroll
        for (int r = 0; r < 4; ++r) {
            int i = ghi * 4 + r;
            if (i < 6 && j < 6) {
                out[attn_base + i * 6 + j] = sv[r];
                s_lds[wid][i * 6 + j] = sv[r];
            }
        }
        __syncthreads();

        float pb[36];
        #pragma unroll
        for (int q4 = 0; q4 < 9; ++q4) {
            float4 t4 = *reinterpret_cast<const float4*>(&s_lds[wid][q4 * 4]);
            pb[q4 * 4 + 0] = t4.x; pb[q4 * 4 + 1] = t4.y;
            pb[q4 * 4 + 2] = t4.z; pb[q4 * 4 + 3] = t4.w;
        }
        #pragma unroll
        for (int i = 0; i < 6; ++i) {
            float c0 = 0.f, c1 = 0.f;
            #pragma unroll
            for (int jj = 0; jj < 6; ++jj) {
                c0 += pb[i * 6 + jj] * v0[jj];
                c1 += pb[i * 6 + jj] * v1[jj];
            }
            out[(size_t)(n * 6 + i) * 1024 + h * 128 + lane] = c0;
            out[(size_t)(n * 6 + i) * 1024 + h * 128 + 64 + lane] = c1;
        }
        __syncthreads();
    }
}

// ---------------------------------------------------------------------------
extern "C" void kernel_launch(void* const* d_in, const int* in_sizes, int n_in,
                              void* d_out, int out_size, void* d_ws, size_t ws_size,
                              hipStream_t stream) {
    const float* emb = (const float*)d_in[0];
    const float* ac  = (const float*)d_in[1];
    const float* Wk  = (const float*)d_in[2];
    const float* bk  = (const float*)d_in[3];
    const float* Wq  = (const float*)d_in[4];
    const float* bq  = (const float*)d_in[5];
    const float* Wg  = (const float*)d_in[6];
    const float* bg  = (const float*)d_in[7];
    float* out = (float*)d_out;

    char* ws = (char*)d_ws;
    u16*   Wt   = (u16*)(ws);                                   //  4 MB
    float* bias = (float*)(ws + 4194304);                       //  8 KB
    float* gate = (float*)(ws + 4194304 + 8192);                //  384 KB
    u16*   QK   = (u16*)(ws + 4194304 + 8192 + 393216);         //  402.7 MB

    pack_w_kernel<<<8192, 256, 0, stream>>>(Wq, Wk, bq, bk, Wt, bias);
    gate_kernel<<<384, 256, 0, stream>>>(ac, Wg, bg, gate);
    qk_gemm_kernel<<<12288, 256, 0, stream>>>(emb, Wt, bias, QK);
    attn_kernel<<<16384, 256, 0, stream>>>(QK, emb, gate, out);
}